// Round 2
// baseline (1046.804 us; speedup 1.0000x reference)
//
#include <hip/hip_runtime.h>
#include <stdint.h>

#define F_N    16384
#define HID    64
#define G3     192            // 3*H
#define ELPF   12288          // 192*64 floats of U_w per f
#define CH4    3072           // float4 chunks per f
#define CHPT   12             // chunks per thread (3072/256)

// ---- kernel 0: global mask popcount (gives both any(mask) and denom) ----
__global__ void count_mask(const int* __restrict__ mask, int* __restrict__ cnt) {
    int i = blockIdx.x * 256 + threadIdx.x;
    int p = (i < F_N) ? (mask[i] != 0) : 0;
    unsigned long long b = __ballot(p);
    if ((threadIdx.x & 63) == 0) atomicAdd(cnt, __popcll(b));
}

// ---- kernel 1: per-f GRU cell, one block per f ----
// U_w row-block (f): 192 rows x 64 cols, row-major. float4 chunk c covers
// floats 4c..4c+3  ->  row i = c>>4, col0 = (c&15)*4.
// Partial dot stored padded at c + (c>>4); U_T[i] = sum_j part[i*17 + j].
__global__ __launch_bounds__(256) void gru_main(
    const float* __restrict__ X,
    const int*   __restrict__ mask,
    const float* __restrict__ Ht,
    const float* __restrict__ xT_w,
    const float* __restrict__ xT_b,
    const float* __restrict__ U_w,
    const int*   __restrict__ cnt,
    float*       __restrict__ agg_slots,   // [64][64]
    float*       __restrict__ out)
{
    __shared__ float hts[HID];
    __shared__ float part[CH4 + G3];   // 3264 floats; chunk c at c + (c>>4)
    __shared__ float xs[G3];
    __shared__ float us[G3];
    __shared__ float xf_s;

    const int f = blockIdx.x;
    const int t = threadIdx.x;

    // stage the 48 KB U_w row-block: fully coalesced 16B-per-lane loads
    const float4* Uv = (const float4*)(U_w + (size_t)f * ELPF);
    float4 u[CHPT];
    #pragma unroll
    for (int k = 0; k < CHPT; ++k) u[k] = Uv[t + 256 * k];

    if (t < HID) hts[t] = Ht[(size_t)f * HID + t];
    if (t == 0)  xf_s = X[f];
    __syncthreads();

    #pragma unroll
    for (int k = 0; k < CHPT; ++k) {
        int c = t + 256 * k;
        const float* h = &hts[(c & 15) << 2];
        float4 v = u[k];
        part[c + (c >> 4)] = v.x * h[0] + v.y * h[1] + v.z * h[2] + v.w * h[3];
    }
    __syncthreads();

    if (t < G3) {
        // stride-17 read: 17 coprime 32 banks -> only the free 2-way aliasing
        float s = 0.f;
        #pragma unroll
        for (int j = 0; j < 16; ++j) s += part[t * 17 + j];
        us[t] = s;
        xs[t] = xT_w[(size_t)f * G3 + t] * xf_s + xT_b[(size_t)f * G3 + t];
    }
    __syncthreads();

    if (t < HID) {
        float xz = xs[t], xr = xs[HID + t], xh = xs[2 * HID + t];
        float uz = us[t], ur = us[HID + t], uh = us[2 * HID + t];
        float z    = 1.f / (1.f + __expf(-(xz + uz)));
        float r    = 1.f / (1.f + __expf(-(xr + ur)));
        float htl  = tanhf(xh + r * uh);
        float htf  = hts[t];
        float hg   = z * htf + (1.f - z) * htl;
        float mf   = (mask[f] != 0) ? 1.f : 0.f;
        bool  anym = (*cnt) > 0;
        float hcur = anym ? (mf * hg) : htf;   // where(m,hg,0) then where(any,.,Ht)
        out[2 + (size_t)f * HID + t] = hcur;
        atomicAdd(&agg_slots[(f & 63) * HID + t], hg * mf);
    }
}

// ---- kernel 2: column-sum finish + 2-layer MLP + softmax ----
__global__ void head(const float* __restrict__ agg_slots,
                     const int*   __restrict__ cnt,
                     const float* __restrict__ W1,
                     const float* __restrict__ b1,
                     const float* __restrict__ W2,
                     const float* __restrict__ b2,
                     float* __restrict__ out)
{
    __shared__ float agg[HID];
    __shared__ float hid[HID];
    const int t = threadIdx.x;   // 64 threads
    float denom = fmaxf((float)(*cnt), 1.f);
    float s = 0.f;
    #pragma unroll 8
    for (int k = 0; k < 64; ++k) s += agg_slots[k * HID + t];
    agg[t] = s / denom;
    __syncthreads();
    float a = b1[t];
    #pragma unroll 8
    for (int h = 0; h < HID; ++h) a += agg[h] * W1[h * HID + t];
    hid[t] = fmaxf(a, 0.f);
    __syncthreads();
    if (t == 0) {
        float l0 = b2[0], l1 = b2[1];
        for (int h = 0; h < HID; ++h) {
            float hv = hid[h];
            l0 += hv * W2[h * 2 + 0];
            l1 += hv * W2[h * 2 + 1];
        }
        float m  = fmaxf(l0, l1);
        float e0 = __expf(l0 - m), e1 = __expf(l1 - m);
        float inv = 1.f / (e0 + e1);
        out[0] = e0 * inv;
        out[1] = e1 * inv;
    }
}

extern "C" void kernel_launch(void* const* d_in, const int* in_sizes, int n_in,
                              void* d_out, int out_size, void* d_ws, size_t ws_size,
                              hipStream_t stream)
{
    // setup_inputs order (all floats are float32 per the reference):
    // 0 tim(int,1) 1 X(f32,F) 2 X_hap(f32,F) 3 mask(int,F) 4 Ht(f32,F*64)
    // 5 xT_w(f32,F*192) 6 xT_b(f32,F*192) 7 U_w(f32,F*192*64)
    // 8 W1(f32,4096) 9 b1(f32,64) 10 W2(f32,128) 11 b2(f32,2)
    const float* X    = (const float*)d_in[1];
    const int*   mask = (const int*)d_in[3];
    const float* Ht   = (const float*)d_in[4];
    const float* xT_w = (const float*)d_in[5];
    const float* xT_b = (const float*)d_in[6];
    const float* U_w  = (const float*)d_in[7];
    const float* W1   = (const float*)d_in[8];
    const float* b1   = (const float*)d_in[9];
    const float* W2   = (const float*)d_in[10];
    const float* b2   = (const float*)d_in[11];
    float* out = (float*)d_out;

    int*   cnt       = (int*)d_ws;
    float* agg_slots = (float*)((char*)d_ws + 256);

    hipMemsetAsync(d_ws, 0, 256 + 64 * HID * sizeof(float), stream);
    count_mask<<<F_N / 256, 256, 0, stream>>>(mask, cnt);
    gru_main<<<F_N, 256, 0, stream>>>(X, mask, Ht, xT_w, xT_b, U_w, cnt, agg_slots, out);
    head<<<1, HID, 0, stream>>>(agg_slots, cnt, W1, b1, W2, b2, out);
}

// Round 3
// 1045.850 us; speedup vs baseline: 1.0009x; 1.0009x over previous
//
#include <hip/hip_runtime.h>
#include <stdint.h>

#define F_N    16384
#define HID    64
#define G3     192            // 3*H
#define ELPF   12288          // 192*64 floats of U_w per f
#define CH4    3072           // float4 chunks per f
#define CHPT   12             // chunks per thread (3072/256)

// ---- kernel 0: global mask popcount (gives both any(mask) and denom) ----
__global__ void count_mask(const int* __restrict__ mask, int* __restrict__ cnt) {
    int i = blockIdx.x * 256 + threadIdx.x;
    int p = (i < F_N) ? (mask[i] != 0) : 0;
    unsigned long long b = __ballot(p);
    if ((threadIdx.x & 63) == 0) atomicAdd(cnt, __popcll(b));
}

// ---- kernel 1: per-f GRU cell, one block per f ----
// U_w row-block (f): 192 rows x 64 cols, row-major. float4 chunk c covers
// floats 4c..4c+3  ->  row i = c>>4, col0 = (c&15)*4.
// Partial dot stored padded at c + (c>>4); U_T[i] = sum_j part[i*17 + j]
// (stride 17 coprime 32 banks -> conflict-free).
// Barrier order: hts barrier FIRST, so the 48 KB U_w burst runs
// load->dot->ds_write with fine-grained vmcnt, no barrier drain inside.
__global__ __launch_bounds__(256) void gru_main(
    const float* __restrict__ X,
    const int*   __restrict__ mask,
    const float* __restrict__ Ht,
    const float* __restrict__ xT_w,
    const float* __restrict__ xT_b,
    const float* __restrict__ U_w,
    const int*   __restrict__ cnt,
    float*       __restrict__ agg_slots,   // [64][64]
    float*       __restrict__ out)
{
    __shared__ float hts[HID];
    __shared__ float part[CH4 + G3];   // 3264 floats; chunk c at c + (c>>4)

    const int f = blockIdx.x;
    const int t = threadIdx.x;

    if (t < HID) hts[t] = Ht[(size_t)f * HID + t];
    __syncthreads();   // A: only the tiny Ht load outstanding here

    const float4* Uv = (const float4*)(U_w + (size_t)f * ELPF);
    #pragma unroll
    for (int k = 0; k < CHPT; ++k) {
        const int c = t + 256 * k;
        float4 v = Uv[c];                       // coalesced 16B/lane
        const float* h = &hts[(c & 15) << 2];   // b128 broadcast groups, conflict-free
        part[c + (c >> 4)] = v.x * h[0] + v.y * h[1] + v.z * h[2] + v.w * h[3];
    }
    __syncthreads();   // B: partials ready

    if (t < HID) {
        float uz = 0.f, ur = 0.f, uh = 0.f;
        #pragma unroll
        for (int j = 0; j < 16; ++j) {
            uz += part[ t         * 17 + j];
            ur += part[(t +  64)  * 17 + j];
            uh += part[(t + 128)  * 17 + j];
        }
        const float xf = X[f];                      // wave-uniform -> scalar load
        const size_t gb = (size_t)f * G3 + t;
        float xz = xT_w[gb]       * xf + xT_b[gb];
        float xr = xT_w[gb + 64]  * xf + xT_b[gb + 64];
        float xh = xT_w[gb + 128] * xf + xT_b[gb + 128];

        float z    = 1.f / (1.f + __expf(-(xz + uz)));
        float r    = 1.f / (1.f + __expf(-(xr + ur)));
        float htl  = tanhf(xh + r * uh);
        float htf  = hts[t];
        float hg   = z * htf + (1.f - z) * htl;
        float mf   = (mask[f] != 0) ? 1.f : 0.f;
        bool  anym = (*cnt) > 0;
        float hcur = anym ? (mf * hg) : htf;   // where(m,hg,0) then where(any,.,Ht)
        out[2 + (size_t)f * HID + t] = hcur;
        atomicAdd(&agg_slots[(f & 63) * HID + t], hg * mf);
    }
}

// ---- kernel 2: column-sum finish + 2-layer MLP + softmax ----
__global__ void head(const float* __restrict__ agg_slots,
                     const int*   __restrict__ cnt,
                     const float* __restrict__ W1,
                     const float* __restrict__ b1,
                     const float* __restrict__ W2,
                     const float* __restrict__ b2,
                     float* __restrict__ out)
{
    __shared__ float agg[HID];
    __shared__ float hid[HID];
    const int t = threadIdx.x;   // 64 threads
    float denom = fmaxf((float)(*cnt), 1.f);
    float s = 0.f;
    #pragma unroll 8
    for (int k = 0; k < 64; ++k) s += agg_slots[k * HID + t];
    agg[t] = s / denom;
    __syncthreads();
    float a = b1[t];
    #pragma unroll 8
    for (int h = 0; h < HID; ++h) a += agg[h] * W1[h * HID + t];
    hid[t] = fmaxf(a, 0.f);
    __syncthreads();
    if (t == 0) {
        float l0 = b2[0], l1 = b2[1];
        for (int h = 0; h < HID; ++h) {
            float hv = hid[h];
            l0 += hv * W2[h * 2 + 0];
            l1 += hv * W2[h * 2 + 1];
        }
        float m  = fmaxf(l0, l1);
        float e0 = __expf(l0 - m), e1 = __expf(l1 - m);
        float inv = 1.f / (e0 + e1);
        out[0] = e0 * inv;
        out[1] = e1 * inv;
    }
}

extern "C" void kernel_launch(void* const* d_in, const int* in_sizes, int n_in,
                              void* d_out, int out_size, void* d_ws, size_t ws_size,
                              hipStream_t stream)
{
    // setup_inputs order (all floats are float32 per the reference):
    // 0 tim(int,1) 1 X(f32,F) 2 X_hap(f32,F) 3 mask(int,F) 4 Ht(f32,F*64)
    // 5 xT_w(f32,F*192) 6 xT_b(f32,F*192) 7 U_w(f32,F*192*64)
    // 8 W1(f32,4096) 9 b1(f32,64) 10 W2(f32,128) 11 b2(f32,2)
    const float* X    = (const float*)d_in[1];
    const int*   mask = (const int*)d_in[3];
    const float* Ht   = (const float*)d_in[4];
    const float* xT_w = (const float*)d_in[5];
    const float* xT_b = (const float*)d_in[6];
    const float* U_w  = (const float*)d_in[7];
    const float* W1   = (const float*)d_in[8];
    const float* b1   = (const float*)d_in[9];
    const float* W2   = (const float*)d_in[10];
    const float* b2   = (const float*)d_in[11];
    float* out = (float*)d_out;

    int*   cnt       = (int*)d_ws;
    float* agg_slots = (float*)((char*)d_ws + 256);

    hipMemsetAsync(d_ws, 0, 256 + 64 * HID * sizeof(float), stream);
    count_mask<<<F_N / 256, 256, 0, stream>>>(mask, cnt);
    gru_main<<<F_N, 256, 0, stream>>>(X, mask, Ht, xT_w, xT_b, U_w, cnt, agg_slots, out);
    head<<<1, HID, 0, stream>>>(agg_slots, cnt, W1, b1, W2, b2, out);
}